// Round 10
// baseline (310.448 us; speedup 1.0000x reference)
//
#include <hip/hip_runtime.h>
#include <hip/hip_bf16.h>
#include <math.h>

// ---------------------------------------------------------------------------
// JointAttention fp16 MFMA pipeline, 5 dispatches:
//   prep (fp32->fp16 x/ctx + pack W^T) -> proj (fused 5-job QKV GEMM,
//   3-buf counted-vmcnt; V written directly in V^T tile layout) ->
//   flash attn (S^T, TK=64, SPLIT-K2, 32x32 MFMA, in-register softmax,
//   glds dbuf 1-barrier) -> combine -> out GEMM (64x64, 3-buf counted-vmcnt).
// R1: proj/out GEMM dbuf 1-barrier; setprio in attn.
// R3: attn on mfma_f32_32x32x16_f16: in-register P via permlane32_swap.
// R4/R5: split-K4 spill/NULL (register file caps 4 waves/SIMD).
// R6/R7: no-LDS direct-global REFUTED (latency-bound).
// R8: attn K/V glds dbuf 1-barrier; proj unmasked at 105us (drain stall).
// R9: proj/out 3-buf 2-deep counted-vmcnt (never vmcnt(0) in loop); proj
//     dropped below attn.
// R10: transpose_v FUSED into proj epilogue (z>=3 writes vt layout directly,
//      same 64B-stride scatter class as kbuf path) -- one dispatch + 32MB
//      round-trip gone. out_gemm retiled 128x64->64x64, grid 512->1024
//      blocks (2->4 blocks/CU): it was grid-starved like pre-R4 attn.
//      Workspace: vt -> old vbuf slot (52MB); osplit -> dead xb/cb (0).
// Swizzle: LDS chunk col c' = c ^ ((row>>1)&3) baked into staging global addr;
//   readers XOR with qsw/ksw.
// Layouts:
//   qbuf [bh][2048][64]              (Q pre-scaled by 0.125*log2e)
//   kbuf [bh][kt64][ks2][tok64][32]  (8KB contiguous staging tiles)
//   vt   [bh][kt64][kks2][d64][32]   (8KB contiguous V^T staging tiles)
//   osplit [s2][bh][2048][64] f16 (normalized partial O)   @ ws+0 (dead xb/cb)
//   lsplit [s2][bh][2048] f32 (partial softmax denom)      @ dead Wq^T region
// ---------------------------------------------------------------------------

typedef _Float16 f16;
typedef _Float16 f16x8 __attribute__((ext_vector_type(8)));
typedef _Float16 f16x4v __attribute__((ext_vector_type(4)));
typedef _Float16 f16x2 __attribute__((ext_vector_type(2)));
typedef float    f32x4 __attribute__((ext_vector_type(4)));
typedef float    f32x16 __attribute__((ext_vector_type(16)));
typedef unsigned u32x4v __attribute__((ext_vector_type(4)));

#define MFMA_F16(a, b, c)  __builtin_amdgcn_mfma_f32_16x16x32_f16((a), (b), (c), 0, 0, 0)
#define MFMA32_F16(a, b, c) __builtin_amdgcn_mfma_f32_32x32x16_f16((a), (b), (c), 0, 0, 0)

#define QSCALE 0.18033688011112042f   // 0.125 * log2(e)

__device__ __forceinline__ void glds16(const f16* g, f16* l) {
    __builtin_amdgcn_global_load_lds(
        (const __attribute__((address_space(1))) void*)g,
        (__attribute__((address_space(3))) void*)l, 16, 0, 0);
}

// RNE f32x2 -> packed f16x2 (matches prior numerics; no RTZ risk)
__device__ __forceinline__ unsigned pk16(float a, float b) {
    f16x2 t = { (f16)a, (f16)b };
    return __builtin_bit_cast(unsigned, t);
}

// ---------------------------------------------------------------------------
// prep: blocks [0,8192) convert x/ctx fp32->fp16; [8192,14336) pack 6 W^T
// ---------------------------------------------------------------------------
__global__ __launch_bounds__(256) void prep(
    const float4* __restrict__ x, const float4* __restrict__ ctx,
    f16x4v* __restrict__ xb, f16x4v* __restrict__ cb,
    const float* __restrict__ W0, const float* __restrict__ W1,
    const float* __restrict__ W2, const float* __restrict__ W3,
    const float* __restrict__ W4, const float* __restrict__ W5,
    f16* __restrict__ wt)
{
    if (blockIdx.x < 8192) {
        const int n4 = (2 * 2048 * 1024) / 4;
        int i = blockIdx.x * 256 + threadIdx.x;
        float4 v;
        f16x4v* dst;
        if (i < n4) { v = x[i];        dst = xb + i; }
        else        { v = ctx[i - n4]; dst = cb + (i - n4); }
        f16x4v h = { (f16)v.x, (f16)v.y, (f16)v.z, (f16)v.w };
        *dst = h;
        return;
    }
    const int idx = blockIdx.x - 8192;
    const int z = idx >> 10, rem = idx & 1023;
    const float* Ws[6] = { W0, W1, W2, W3, W4, W5 };
    const float* W = Ws[z];
    f16* Wt = wt + (size_t)z * (1024 * 1024);

    __shared__ float tile[32][33];
    const int tx = threadIdx.x & 31, ty = threadIdx.x >> 5;
    const int n0 = (rem & 31) * 32, k0 = (rem >> 5) * 32;

#pragma unroll
    for (int i = 0; i < 4; ++i) {
        int r = i * 8 + ty;
        tile[r][tx] = W[(size_t)(k0 + r) * 1024 + n0 + tx];
    }
    __syncthreads();
#pragma unroll
    for (int i = 0; i < 4; ++i) {
        int r = i * 8 + ty;
        Wt[(size_t)(n0 + r) * 1024 + k0 + tx] = (f16)tile[tx][r];
    }
}

// Shared GEMM prologue (128-row A tile, BN-row B tile, BK=32, swizzled glds)
#define GEMM_PROLOGUE(BN)                                                     \
    const int m0 = blockIdx.x * 128, n0 = blockIdx.y * (BN);                  \
    const int tid = threadIdx.x;                                              \
    const int w = tid >> 6, lane = tid & 63, quad = lane >> 4, l15 = lane & 15;\
    const int wm = (w >> 1) * 64, wn = (w & 1) * ((BN) / 2);                  \
    const int qsw = (quad ^ ((l15 >> 1) & 3)) * 8;                            \
    int gA[2], gB[(BN) / 64];                                                 \
    _Pragma("unroll")                                                         \
    for (int p = 0; p < 2; ++p) {                                             \
        int s = tid + p * 256;                                                \
        int r = (s >> 2) & 127, c = (s & 3) ^ ((s >> 3) & 3);                 \
        gA[p] = (m0 + r) * 1024 + c * 8;                                      \
    }                                                                         \
    _Pragma("unroll")                                                         \
    for (int p = 0; p < (BN) / 64; ++p) {                                     \
        int s = tid + p * 256;                                                \
        int r = (s >> 2) & ((BN) - 1), c = (s & 3) ^ ((s >> 3) & 3);          \
        gB[p] = (n0 + r) * 1024 + c * 8;                                      \
    }

// Stage K-chunk koff into LDS buffer `buf` (no barriers; caller owns sync)
#define GEMM_STAGE_TO(BN, buf, koff)                                          \
    _Pragma("unroll")                                                         \
    for (int p = 0; p < 2; ++p)                                               \
        glds16(&A[gA[p] + (koff)], &As[buf][(p * 256 + w * 64) * 8]);         \
    _Pragma("unroll")                                                         \
    for (int p = 0; p < (BN) / 64; ++p)                                       \
        glds16(&Bt[gB[p] + (koff)], &Bs[buf][(p * 256 + w * 64) * 8]);

// ---------------------------------------------------------------------------
// Fused projection GEMM. z: 0=Q 1=K_self 2=K_ctx 3=V_self 4=V_ctx
// R9: 3-buffer 2-deep counted-vmcnt pipeline (T4). 4 glds/stage ->
// steady-state wait = vmcnt(4). LDS 48KB, 3 blocks/CU.
// R10: z>=3 epilogue writes vt tile layout directly (transpose_v fused).
// ---------------------------------------------------------------------------
__global__ __launch_bounds__(256) void proj_gemm(
    const f16* __restrict__ xb, const f16* __restrict__ cb,
    const f16* __restrict__ wt,
    const float* __restrict__ bq, const float* __restrict__ bks,
    const float* __restrict__ bkc, const float* __restrict__ bvs,
    const float* __restrict__ bvc,
    f16* __restrict__ qbuf, f16* __restrict__ kbuf, f16* __restrict__ vtb)
{
    __shared__ alignas(16) f16 As[3][128 * 32];
    __shared__ alignas(16) f16 Bs[3][128 * 32];

    const int z = blockIdx.z;
    const f16* A = (z == 0 || z == 1 || z == 3) ? xb : cb;
    const int wslot = (z == 0) ? 0 : (z == 1) ? 1 : (z == 2) ? 3 : (z == 3) ? 2 : 4;
    const f16* Bt = wt + (size_t)wslot * 1048576;
    const float* bias = (z == 0) ? bq : (z == 1) ? bks : (z == 2) ? bkc
                        : (z == 3) ? bvs : bvc;
    const int roff = (z == 2 || z == 4) ? 2048 : 0;

    GEMM_PROLOGUE(128)
    f32x4 acc[4][4] = {};

    GEMM_STAGE_TO(128, 0, 0)
    GEMM_STAGE_TO(128, 1, 32)

    for (int it = 0; it < 32; ++it) {
        // wait own glds(it) done (tile it+1's 4 loads may stay in flight)
        if (it < 31) { asm volatile("s_waitcnt vmcnt(4)" ::: "memory"); }
        else         { asm volatile("s_waitcnt vmcnt(0)" ::: "memory"); }
        __builtin_amdgcn_s_barrier();   // all waves' tile-it loads complete;
                                        // all waves done reading buf (it+2)%3
        if (it + 2 < 32) {
            GEMM_STAGE_TO(128, (it + 2) % 3, (it + 2) * 32)
        }
        const f16* Asc = As[it % 3];
        const f16* Bsc = Bs[it % 3];
        f16x8 a[4], b[4];
#pragma unroll
        for (int i = 0; i < 4; ++i)
            a[i] = *(const f16x8*)&Asc[(wm + i * 16 + l15) * 32 + qsw];
#pragma unroll
        for (int i = 0; i < 4; ++i)
            b[i] = *(const f16x8*)&Bsc[(wn + i * 16 + l15) * 32 + qsw];
#pragma unroll
        for (int mi = 0; mi < 4; ++mi)
#pragma unroll
            for (int ni = 0; ni < 4; ++ni)
                acc[mi][ni] = MFMA_F16(a[mi], b[ni], acc[mi][ni]);
    }

#pragma unroll
    for (int mi = 0; mi < 4; ++mi) {
#pragma unroll
        for (int r = 0; r < 4; ++r) {
            int row = m0 + wm + mi * 16 + quad * 4 + r;
            int b_ = row >> 11, tok = row & 2047;
#pragma unroll
            for (int ni = 0; ni < 4; ++ni) {
                int col = n0 + wn + ni * 16 + l15;
                float v = acc[mi][ni][r] + bias[col];
                int bh = b_ * 16 + (col >> 6);
                int tg = roff + tok;
                if (z == 0) {
                    qbuf[((size_t)bh * 2048 + tok) * 64 + (col & 63)] = (f16)(v * QSCALE);
                } else if (z <= 2) {
                    kbuf[(size_t)bh * 262144 + (size_t)(tg >> 6) * 4096
                         + (size_t)((col >> 5) & 1) * 2048 + (tg & 63) * 32 + (col & 31)] = (f16)v;
                } else {
                    // direct V^T tile write: vt[bh][tg>>6][(tg>>5)&1][d][tg&31]
                    vtb[(size_t)bh * 262144 + (size_t)(tg >> 6) * 4096
                        + (size_t)((tg >> 5) & 1) * 2048 + (col & 63) * 32 + (tg & 31)] = (f16)v;
                }
            }
        }
    }
}

// ---------------------------------------------------------------------------
// Flash attention, S^T form, TK=64, SPLIT-K2 (each split: 32 key-tiles).
// Grid (bh=32, qt=16, s=2) = 1024 blocks = 4/CU (register-capped). 4 waves;
// wave owns 32 q-rows = the 32 columns of one 32x32 MFMA.
// R8: K/V glds DOUBLE-buffer, ONE barrier per tile.
// ---------------------------------------------------------------------------
__global__ __launch_bounds__(256, 4) void attn_kernel(
    const f16* __restrict__ q, const f16* __restrict__ kb,
    const f16* __restrict__ vtb, f16* __restrict__ osplit,
    float* __restrict__ lsplit)
{
    __shared__ alignas(16) f16 K_lds[2][4096];     // [buf][ks2][tok64][32]
    __shared__ alignas(16) f16 V_lds[2][4096];     // [buf][kks2][d64][32]

    const int tid = threadIdx.x;
    const int w = tid >> 6, lane = tid & 63;
    const int l31 = lane & 31, h = lane >> 5;
    const int bh = blockIdx.x, qt = blockIdx.y, sp = blockIdx.z;
    const int qbase = qt * 128;

    // Q fragments: B[q = l31][k = kc*16 + h*8 + j]
    f16x8 qa[4];
    {
        const size_t qrow = ((size_t)bh * 2048 + qbase + w * 32 + l31) * 64;
#pragma unroll
        for (int kc = 0; kc < 4; ++kc)
            qa[kc] = *(const f16x8*)&q[qrow + kc * 16 + h * 8];
    }

    f32x16 o_acc[2] = {};   // O^T[d = db*32 + (reg&3)+8*(reg>>2)+4h][q = l31]
    float l_part = 0.f;

    const f16* ktile = kb + (size_t)bh * 262144 + (size_t)sp * 131072;
    const f16* vtile = vtb + (size_t)bh * 262144 + (size_t)sp * 131072;

    const int sco = ((tid >> 2) * 4 + ((tid & 3) ^ ((tid >> 3) & 3))) * 8;
    const int ksw = (l31 >> 1) & 3;                // staging swizzle un-XOR
    const int wslot = w * 512;

    // tile 0 -> buf 0 via async glds (drained by first loop barrier)
    glds16(ktile + sco,        &K_lds[0][wslot]);
    glds16(ktile + 2048 + sco, &K_lds[0][2048 + wslot]);
    glds16(vtile + sco,        &V_lds[0][wslot]);
    glds16(vtile + 2048 + sco, &V_lds[0][2048 + wslot]);

    for (int kt = 0; kt < 32; ++kt) {
        const int cur = kt & 1;
        const f16* Kc = K_lds[cur];
        const f16* Vc = V_lds[cur];

        __syncthreads();   // glds(kt) drained; all waves done with buf cur^1

        // prefetch tile kt+1 into buf cur^1; overlaps compute of kt
        if (kt != 31) {
            ktile += 4096; vtile += 4096;
            glds16(ktile + sco,        &K_lds[cur ^ 1][wslot]);
            glds16(ktile + 2048 + sco, &K_lds[cur ^ 1][2048 + wslot]);
            glds16(vtile + sco,        &V_lds[cur ^ 1][wslot]);
            glds16(vtile + 2048 + sco, &V_lds[cur ^ 1][2048 + wslot]);
        }

#pragma unroll
        for (int mt = 0; mt < 2; ++mt) {
            // QK^T: A = K[tok = mt*32+l31][k], B = Q[q][k]
            f32x16 s = {};
            __builtin_amdgcn_s_setprio(1);
#pragma unroll
            for (int kc = 0; kc < 4; ++kc) {
                f16x8 ka = *(const f16x8*)&Kc[(kc >> 1) * 2048
                             + (mt * 32 + l31) * 32
                             + ((((kc & 1) * 2 + h) ^ ksw)) * 8];
                s = MFMA32_F16(ka, qa[kc], s);
            }
            __builtin_amdgcn_s_setprio(0);

            float pe[16];
#pragma unroll
            for (int i = 0; i < 16; ++i) pe[i] = __builtin_amdgcn_exp2f(s[i]);

            {   // l partial: rows with bit2 == h (partner half added in epilogue)
                float t0 = (pe[0] + pe[1]) + (pe[2] + pe[3]);
                float t1 = (pe[4] + pe[5]) + (pe[6] + pe[7]);
                float t2 = (pe[8] + pe[9]) + (pe[10] + pe[11]);
                float t3 = (pe[12] + pe[13]) + (pe[14] + pe[15]);
                l_part += (t0 + t1) + (t2 + t3);
            }

#pragma unroll
            for (int c = 0; c < 2; ++c) {
                // chunk c: regs cb..cb+7 hold in-chunk kk {4h..4h+3} u {8+4h..}
                const int cb = c * 8;
                unsigned X0 = pk16(pe[cb + 0], pe[cb + 1]);
                unsigned X1 = pk16(pe[cb + 2], pe[cb + 3]);
                unsigned Y0 = pk16(pe[cb + 4], pe[cb + 5]);
                unsigned Y1 = pk16(pe[cb + 6], pe[cb + 7]);
                // dst.hi <-> src.lo: r[0] = {X.lo, Y.lo}, r[1] = {X.hi, Y.hi}
                auto r0 = __builtin_amdgcn_permlane32_swap(X0, Y0, false, false);
                auto r1 = __builtin_amdgcn_permlane32_swap(X1, Y1, false, false);
                u32x4v pw;
                pw[0] = r0[0]; pw[1] = r1[0]; pw[2] = r0[1]; pw[3] = r1[1];
                f16x8 pfrag = __builtin_bit_cast(f16x8, pw);  // B[q][kk = 8h+j]

                const int kchunk = mt * 2 + c;
                __builtin_amdgcn_s_setprio(1);
#pragma unroll
                for (int db = 0; db < 2; ++db) {
                    f16x8 va = *(const f16x8*)&Vc[(kchunk >> 1) * 2048
                                 + (db * 32 + l31) * 32
                                 + (((((kchunk & 1) * 2 + h)) ^ ksw)) * 8];
                    o_acc[db] = MFMA32_F16(va, pfrag, o_acc[db]);
                }
                __builtin_amdgcn_s_setprio(0);
            }
        }
    }

    // epilogue: l = own half + partner half; write O^/l (f16) and l (f32).
    float lf = l_part + __shfl_xor(l_part, 32, 64);
    float inv = 1.0f / lf;
    const int row = w * 32 + l31;
    const size_t sb = (size_t)(sp * 32 + bh) * 2048 + qbase;
    if (h == 0) lsplit[sb + row] = lf;
    const size_t obase = (sb + row) * 64;
#pragma unroll
    for (int db = 0; db < 2; ++db) {
#pragma unroll
        for (int g = 0; g < 4; ++g) {
            f16x4v ov;
#pragma unroll
            for (int i = 0; i < 4; ++i)
                ov[i] = (f16)(o_acc[db][g * 4 + i] * inv);
            *(f16x4v*)&osplit[obase + db * 32 + g * 8 + h * 4] = ov;
        }
    }
}

// ---------------------------------------------------------------------------
// combine: abuf[b*2048+row][h*64+d] = (l1*O1^ + l2*O2^) / (l1+l2)
// ---------------------------------------------------------------------------
__global__ __launch_bounds__(256) void combine(
    const f16* __restrict__ osplit, const float* __restrict__ lsplit,
    f16* __restrict__ abuf)
{
    int idx = blockIdx.x * 256 + threadIdx.x;     // 524288 total
    int d8 = idx & 7;
    int row = (idx >> 3) & 2047;
    int bh = idx >> 14;
    int b = bh >> 4, h = bh & 15;
    size_t base1 = ((size_t)bh * 2048 + row) * 64 + d8 * 8;
    size_t base2 = ((size_t)(32 + bh) * 2048 + row) * 64 + d8 * 8;
    float l1 = lsplit[bh * 2048 + row];
    float l2 = lsplit[65536 + bh * 2048 + row];
    float inv = 1.0f / (l1 + l2);
    float w1 = l1 * inv, w2 = l2 * inv;
    f16x8 a = *(const f16x8*)&osplit[base1];
    f16x8 c = *(const f16x8*)&osplit[base2];
    f16x8 out;
#pragma unroll
    for (int j = 0; j < 8; ++j)
        out[j] = (f16)(w1 * (float)a[j] + w2 * (float)c[j]);
    *(f16x8*)&abuf[((size_t)(b * 2048 + row)) * 1024 + h * 64 + d8 * 8] = out;
}

// ---------------------------------------------------------------------------
// Output GEMM, R10: 64x64 tiles, grid (64,16) = 1024 blocks (4 blocks/CU,
// was 2). 3-buffer 2-deep counted-vmcnt pipeline; 2 glds/stage -> vmcnt(2).
// LDS = 3*(4+4) KB = 24 KB. fp32 out + bias.
// ---------------------------------------------------------------------------
__global__ __launch_bounds__(256) void out_gemm(
    const f16* __restrict__ abuf, const f16* __restrict__ wt5,
    const float* __restrict__ bo, float* __restrict__ out)
{
    __shared__ alignas(16) f16 As[3][64 * 32];
    __shared__ alignas(16) f16 Bs[3][64 * 32];

    const int m0 = blockIdx.x * 64, n0 = blockIdx.y * 64;
    const int tid = threadIdx.x;
    const int w = tid >> 6, lane = tid & 63, quad = lane >> 4, l15 = lane & 15;
    const int wm = (w >> 1) * 32, wn = (w & 1) * 32;
    const int qsw = (quad ^ ((l15 >> 1) & 3)) * 8;
    const int r_ = (tid >> 2) & 63, c_ = (tid & 3) ^ ((tid >> 3) & 3);
    const int gA = (m0 + r_) * 1024 + c_ * 8;
    const int gB = (n0 + r_) * 1024 + c_ * 8;

    f32x4 acc[2][2] = {};

#define OUT_STAGE(buf, koff)                                                  \
    glds16(&abuf[gA + (koff)], &As[buf][w * 512]);                            \
    glds16(&wt5[gB + (koff)],  &Bs[buf][w * 512]);

    OUT_STAGE(0, 0)
    OUT_STAGE(1, 32)

    for (int it = 0; it < 32; ++it) {
        if (it < 31) { asm volatile("s_waitcnt vmcnt(2)" ::: "memory"); }
        else         { asm volatile("s_waitcnt vmcnt(0)" ::: "memory"); }
        __builtin_amdgcn_s_barrier();
        if (it + 2 < 32) {
            OUT_STAGE((it + 2) % 3, (it + 2) * 32)
        }
        const f16* Asc = As[it % 3];
        const f16* Bsc = Bs[it % 3];
        f16x8 a[2], b[2];
#pragma unroll
        for (int i = 0; i < 2; ++i)
            a[i] = *(const f16x8*)&Asc[(wm + i * 16 + l15) * 32 + qsw];
#pragma unroll
        for (int i = 0; i < 2; ++i)
            b[i] = *(const f16x8*)&Bsc[(wn + i * 16 + l15) * 32 + qsw];
#pragma unroll
        for (int mi = 0; mi < 2; ++mi)
#pragma unroll
            for (int ni = 0; ni < 2; ++ni)
                acc[mi][ni] = MFMA_F16(a[mi], b[ni], acc[mi][ni]);
    }

#pragma unroll
    for (int mi = 0; mi < 2; ++mi) {
#pragma unroll
        for (int r = 0; r < 4; ++r) {
            int row = m0 + wm + mi * 16 + quad * 4 + r;
#pragma unroll
            for (int ni = 0; ni < 2; ++ni) {
                int col = n0 + wn + ni * 16 + l15;
                out[(size_t)row * 1024 + col] = acc[mi][ni][r] + bo[col];
            }
        }
    }
}

// ---------------------------------------------------------------------------
// Host launcher
// ---------------------------------------------------------------------------
extern "C" void kernel_launch(void* const* d_in, const int* in_sizes, int n_in,
                              void* d_out, int out_size, void* d_ws, size_t ws_size,
                              hipStream_t stream)
{
    (void)in_sizes; (void)n_in; (void)out_size; (void)ws_size;

    const float* x    = (const float*)d_in[0];
    const float* ctx  = (const float*)d_in[1];
    const float* Wq   = (const float*)d_in[2];  const float* bq  = (const float*)d_in[3];
    const float* Wks  = (const float*)d_in[4];  const float* bks = (const float*)d_in[5];
    const float* Wvs  = (const float*)d_in[6];  const float* bvs = (const float*)d_in[7];
    const float* Wkc  = (const float*)d_in[8];  const float* bkc = (const float*)d_in[9];
    const float* Wvc  = (const float*)d_in[10]; const float* bvc = (const float*)d_in[11];
    const float* Wo   = (const float*)d_in[12]; const float* bo  = (const float*)d_in[13];

    char* ws = (char*)d_ws;
    f16*   xb     = (f16*)(ws + 0);          //  8 MB (dead after proj)
    f16*   cb     = (f16*)(ws + 8388608);    //  8 MB (dead after proj)
    f16*   osplit = (f16*)(ws + 0);          // 16 MB, reuses dead xb/cb
    f16*   wt     = (f16*)(ws + 16777216);   // 12 MB 6 x [1024][1024]
    float* lsplit = (float*)(ws + 16777216); // 512 KB, reuses dead Wq^T slice
    f16*   qbuf   = (f16*)(ws + 29360128);   //  8 MB [bh][2048][64]
    f16*   kbuf   = (f16*)(ws + 37748736);   // 16 MB K tiles
    f16*   vt     = (f16*)(ws + 54525952);   // 16 MB V^T tiles (proj-direct)
    f16*   abuf   = (f16*)(ws + 71303168);   //  8 MB (end 79,691,776)

    prep<<<14336, 256, 0, stream>>>((const float4*)x, (const float4*)ctx,
                                    (f16x4v*)xb, (f16x4v*)cb,
                                    Wq, Wks, Wvs, Wkc, Wvc, Wo, wt);

    proj_gemm<<<dim3(32, 8, 5), 256, 0, stream>>>(
        xb, cb, wt, bq, bks, bkc, bvs, bvc, qbuf, kbuf, vt);

    attn_kernel<<<dim3(32, 16, 2), 256, 0, stream>>>(qbuf, kbuf, vt, osplit, lsplit);

    combine<<<2048, 256, 0, stream>>>(osplit, lsplit, abuf);

    out_gemm<<<dim3(64, 16), 256, 0, stream>>>(abuf, wt + 5 * 1048576, bo, (float*)d_out);
}

// Round 11
// 307.403 us; speedup vs baseline: 1.0099x; 1.0099x over previous
//
#include <hip/hip_runtime.h>
#include <hip/hip_bf16.h>
#include <math.h>

// ---------------------------------------------------------------------------
// JointAttention fp16 MFMA pipeline, 5 dispatches:
//   prep (fp32->fp16 x/ctx + pack W^T) -> proj (fused 5-job QKV GEMM,
//   3-buf counted-vmcnt) -> transpose_v -> flash attn (S^T, TK=64, SPLIT-K2,
//   32x32 MFMA, in-register softmax, glds dbuf 1-barrier) ->
//   out GEMM (64x64, combine FUSED into reg-staged A).
// R1: proj/out GEMM dbuf 1-barrier; setprio in attn.
// R3: attn on mfma_f32_32x32x16_f16: in-register P via permlane32_swap.
// R4/R5: split-K4 spill/NULL (register file caps 4 waves/SIMD).
// R6/R7: no-LDS direct-global REFUTED (latency-bound).
// R8: attn K/V glds dbuf 1-barrier. R9: proj/out counted-vmcnt pipeline.
// R10: proj V^T-direct write REGRESSED (~+25us: 64B-stride scatter, zero
//      contiguity) -- reverted; transpose_v restored. out 64x64 kept.
// R11: combine dispatch DELETED: out_gemm A-stage is reg-staged
//      (a1,a2 f16x8 + l1,l2 scalars -> merge -> ds_write_b128); per-thread
//      row is FIXED across K-iters so merge weights reload only per h=it>>1.
//      B stays glds, 3-buf 2-deep; iter end = lgkmcnt(0) + raw s_barrier
//      (B(it+2) stays in flight across barrier, T4). Self-ordering: wait
//      for a(it+1) at merge drains B(it+1) (issued earlier in vmem order).
// Swizzle: LDS chunk col c' = c ^ ((row>>1)&3) baked into staging global addr;
//   readers XOR with qsw/ksw.
// Layouts:
//   qbuf [bh][2048][64]              (Q pre-scaled by 0.125*log2e)
//   kbuf [bh][kt64][ks2][tok64][32]  (8KB contiguous staging tiles)
//   vbuf [bh][4096][64]  -> dead after transpose_v, reused as osplit
//   vt   [bh][kt64][kks2][d64][32]   (8KB contiguous V^T staging tiles)
//   osplit [s2][bh][2048][64] f16 (normalized partial O)   @ vbuf region
//   lsplit [s2][bh][2048] f32 (partial softmax denom)      @ dead Wq^T region
// ---------------------------------------------------------------------------

typedef _Float16 f16;
typedef _Float16 f16x8 __attribute__((ext_vector_type(8)));
typedef _Float16 f16x4v __attribute__((ext_vector_type(4)));
typedef _Float16 f16x2 __attribute__((ext_vector_type(2)));
typedef float    f32x4 __attribute__((ext_vector_type(4)));
typedef float    f32x16 __attribute__((ext_vector_type(16)));
typedef unsigned u32x4v __attribute__((ext_vector_type(4)));

#define MFMA_F16(a, b, c)  __builtin_amdgcn_mfma_f32_16x16x32_f16((a), (b), (c), 0, 0, 0)
#define MFMA32_F16(a, b, c) __builtin_amdgcn_mfma_f32_32x32x16_f16((a), (b), (c), 0, 0, 0)

#define QSCALE 0.18033688011112042f   // 0.125 * log2(e)

__device__ __forceinline__ void glds16(const f16* g, f16* l) {
    __builtin_amdgcn_global_load_lds(
        (const __attribute__((address_space(1))) void*)g,
        (__attribute__((address_space(3))) void*)l, 16, 0, 0);
}

// RNE f32x2 -> packed f16x2 (matches prior numerics; no RTZ risk)
__device__ __forceinline__ unsigned pk16(float a, float b) {
    f16x2 t = { (f16)a, (f16)b };
    return __builtin_bit_cast(unsigned, t);
}

// ---------------------------------------------------------------------------
// prep: blocks [0,8192) convert x/ctx fp32->fp16; [8192,14336) pack 6 W^T
// ---------------------------------------------------------------------------
__global__ __launch_bounds__(256) void prep(
    const float4* __restrict__ x, const float4* __restrict__ ctx,
    f16x4v* __restrict__ xb, f16x4v* __restrict__ cb,
    const float* __restrict__ W0, const float* __restrict__ W1,
    const float* __restrict__ W2, const float* __restrict__ W3,
    const float* __restrict__ W4, const float* __restrict__ W5,
    f16* __restrict__ wt)
{
    if (blockIdx.x < 8192) {
        const int n4 = (2 * 2048 * 1024) / 4;
        int i = blockIdx.x * 256 + threadIdx.x;
        float4 v;
        f16x4v* dst;
        if (i < n4) { v = x[i];        dst = xb + i; }
        else        { v = ctx[i - n4]; dst = cb + (i - n4); }
        f16x4v h = { (f16)v.x, (f16)v.y, (f16)v.z, (f16)v.w };
        *dst = h;
        return;
    }
    const int idx = blockIdx.x - 8192;
    const int z = idx >> 10, rem = idx & 1023;
    const float* Ws[6] = { W0, W1, W2, W3, W4, W5 };
    const float* W = Ws[z];
    f16* Wt = wt + (size_t)z * (1024 * 1024);

    __shared__ float tile[32][33];
    const int tx = threadIdx.x & 31, ty = threadIdx.x >> 5;
    const int n0 = (rem & 31) * 32, k0 = (rem >> 5) * 32;

#pragma unroll
    for (int i = 0; i < 4; ++i) {
        int r = i * 8 + ty;
        tile[r][tx] = W[(size_t)(k0 + r) * 1024 + n0 + tx];
    }
    __syncthreads();
#pragma unroll
    for (int i = 0; i < 4; ++i) {
        int r = i * 8 + ty;
        Wt[(size_t)(n0 + r) * 1024 + k0 + tx] = (f16)tile[tx][r];
    }
}

// Shared GEMM prologue (128-row A tile, BN-row B tile, BK=32, swizzled glds)
#define GEMM_PROLOGUE(BN)                                                     \
    const int m0 = blockIdx.x * 128, n0 = blockIdx.y * (BN);                  \
    const int tid = threadIdx.x;                                              \
    const int w = tid >> 6, lane = tid & 63, quad = lane >> 4, l15 = lane & 15;\
    const int wm = (w >> 1) * 64, wn = (w & 1) * ((BN) / 2);                  \
    const int qsw = (quad ^ ((l15 >> 1) & 3)) * 8;                            \
    int gA[2], gB[(BN) / 64];                                                 \
    _Pragma("unroll")                                                         \
    for (int p = 0; p < 2; ++p) {                                             \
        int s = tid + p * 256;                                                \
        int r = (s >> 2) & 127, c = (s & 3) ^ ((s >> 3) & 3);                 \
        gA[p] = (m0 + r) * 1024 + c * 8;                                      \
    }                                                                         \
    _Pragma("unroll")                                                         \
    for (int p = 0; p < (BN) / 64; ++p) {                                     \
        int s = tid + p * 256;                                                \
        int r = (s >> 2) & ((BN) - 1), c = (s & 3) ^ ((s >> 3) & 3);          \
        gB[p] = (n0 + r) * 1024 + c * 8;                                      \
    }

// Stage K-chunk koff into LDS buffer `buf` (no barriers; caller owns sync)
#define GEMM_STAGE_TO(BN, buf, koff)                                          \
    _Pragma("unroll")                                                         \
    for (int p = 0; p < 2; ++p)                                               \
        glds16(&A[gA[p] + (koff)], &As[buf][(p * 256 + w * 64) * 8]);         \
    _Pragma("unroll")                                                         \
    for (int p = 0; p < (BN) / 64; ++p)                                       \
        glds16(&Bt[gB[p] + (koff)], &Bs[buf][(p * 256 + w * 64) * 8]);

// ---------------------------------------------------------------------------
// Fused projection GEMM. z: 0=Q 1=K_self 2=K_ctx 3=V_self 4=V_ctx
// R9: 3-buffer 2-deep counted-vmcnt pipeline (T4). 4 glds/stage ->
// steady-state wait = vmcnt(4). LDS 48KB, 3 blocks/CU.
// ---------------------------------------------------------------------------
__global__ __launch_bounds__(256) void proj_gemm(
    const f16* __restrict__ xb, const f16* __restrict__ cb,
    const f16* __restrict__ wt,
    const float* __restrict__ bq, const float* __restrict__ bks,
    const float* __restrict__ bkc, const float* __restrict__ bvs,
    const float* __restrict__ bvc,
    f16* __restrict__ qbuf, f16* __restrict__ kbuf, f16* __restrict__ vbuf)
{
    __shared__ alignas(16) f16 As[3][128 * 32];
    __shared__ alignas(16) f16 Bs[3][128 * 32];

    const int z = blockIdx.z;
    const f16* A = (z == 0 || z == 1 || z == 3) ? xb : cb;
    const int wslot = (z == 0) ? 0 : (z == 1) ? 1 : (z == 2) ? 3 : (z == 3) ? 2 : 4;
    const f16* Bt = wt + (size_t)wslot * 1048576;
    const float* bias = (z == 0) ? bq : (z == 1) ? bks : (z == 2) ? bkc
                        : (z == 3) ? bvs : bvc;
    const int roff = (z == 2 || z == 4) ? 2048 : 0;

    GEMM_PROLOGUE(128)
    f32x4 acc[4][4] = {};

    GEMM_STAGE_TO(128, 0, 0)
    GEMM_STAGE_TO(128, 1, 32)

    for (int it = 0; it < 32; ++it) {
        // wait own glds(it) done (tile it+1's 4 loads may stay in flight)
        if (it < 31) { asm volatile("s_waitcnt vmcnt(4)" ::: "memory"); }
        else         { asm volatile("s_waitcnt vmcnt(0)" ::: "memory"); }
        __builtin_amdgcn_s_barrier();   // all waves' tile-it loads complete;
                                        // all waves done reading buf (it+2)%3
        if (it + 2 < 32) {
            GEMM_STAGE_TO(128, (it + 2) % 3, (it + 2) * 32)
        }
        const f16* Asc = As[it % 3];
        const f16* Bsc = Bs[it % 3];
        f16x8 a[4], b[4];
#pragma unroll
        for (int i = 0; i < 4; ++i)
            a[i] = *(const f16x8*)&Asc[(wm + i * 16 + l15) * 32 + qsw];
#pragma unroll
        for (int i = 0; i < 4; ++i)
            b[i] = *(const f16x8*)&Bsc[(wn + i * 16 + l15) * 32 + qsw];
#pragma unroll
        for (int mi = 0; mi < 4; ++mi)
#pragma unroll
            for (int ni = 0; ni < 4; ++ni)
                acc[mi][ni] = MFMA_F16(a[mi], b[ni], acc[mi][ni]);
    }

#pragma unroll
    for (int mi = 0; mi < 4; ++mi) {
#pragma unroll
        for (int r = 0; r < 4; ++r) {
            int row = m0 + wm + mi * 16 + quad * 4 + r;
            int b_ = row >> 11, tok = row & 2047;
#pragma unroll
            for (int ni = 0; ni < 4; ++ni) {
                int col = n0 + wn + ni * 16 + l15;
                float v = acc[mi][ni][r] + bias[col];
                int bh = b_ * 16 + (col >> 6);
                int tg = roff + tok;
                if (z == 0) {
                    qbuf[((size_t)bh * 2048 + tok) * 64 + (col & 63)] = (f16)(v * QSCALE);
                } else if (z <= 2) {
                    kbuf[(size_t)bh * 262144 + (size_t)(tg >> 6) * 4096
                         + (size_t)((col >> 5) & 1) * 2048 + (tg & 63) * 32 + (col & 31)] = (f16)v;
                } else {
                    vbuf[(size_t)bh * 262144 + (size_t)tg * 64 + (col & 63)] = (f16)v;
                }
            }
        }
    }
}

// ---------------------------------------------------------------------------
// V transpose: vbuf [bh][4096][64] -> vt tiles [bh][kt64][kks2][d64][32kk]
// ---------------------------------------------------------------------------
__global__ __launch_bounds__(256) void transpose_v(
    const f16* __restrict__ vbuf, f16* __restrict__ vt)
{
    const int t = threadIdx.x;
    const int mt = t >> 3, md = t & 7;
    const int tok0 = blockIdx.x * 256 + mt * 8;
    const int z = blockIdx.y;                   // bh
    f16x8 in[8];
#pragma unroll
    for (int i = 0; i < 8; ++i)
        in[i] = *(const f16x8*)&vbuf[((size_t)z * 4096 + tok0 + i) * 64 + md * 8];
    f16x8 ov[8];
#pragma unroll
    for (int j = 0; j < 8; ++j)
#pragma unroll
        for (int i = 0; i < 8; ++i) ov[j][i] = in[i][j];
    const int kt = tok0 >> 6, kks = (tok0 >> 5) & 1, kko = tok0 & 31;
#pragma unroll
    for (int j = 0; j < 8; ++j)
        *(f16x8*)&vt[(size_t)z * 262144 + (size_t)kt * 4096 + kks * 2048
                     + (md * 8 + j) * 32 + kko] = ov[j];
}

// ---------------------------------------------------------------------------
// Flash attention, S^T form, TK=64, SPLIT-K2 (each split: 32 key-tiles).
// Grid (bh=32, qt=16, s=2) = 1024 blocks = 4/CU (register-capped). 4 waves;
// wave owns 32 q-rows = the 32 columns of one 32x32 MFMA.
// R8: K/V glds DOUBLE-buffer, ONE barrier per tile.
// ---------------------------------------------------------------------------
__global__ __launch_bounds__(256, 4) void attn_kernel(
    const f16* __restrict__ q, const f16* __restrict__ kb,
    const f16* __restrict__ vtb, f16* __restrict__ osplit,
    float* __restrict__ lsplit)
{
    __shared__ alignas(16) f16 K_lds[2][4096];     // [buf][ks2][tok64][32]
    __shared__ alignas(16) f16 V_lds[2][4096];     // [buf][kks2][d64][32]

    const int tid = threadIdx.x;
    const int w = tid >> 6, lane = tid & 63;
    const int l31 = lane & 31, h = lane >> 5;
    const int bh = blockIdx.x, qt = blockIdx.y, sp = blockIdx.z;
    const int qbase = qt * 128;

    // Q fragments: B[q = l31][k = kc*16 + h*8 + j]
    f16x8 qa[4];
    {
        const size_t qrow = ((size_t)bh * 2048 + qbase + w * 32 + l31) * 64;
#pragma unroll
        for (int kc = 0; kc < 4; ++kc)
            qa[kc] = *(const f16x8*)&q[qrow + kc * 16 + h * 8];
    }

    f32x16 o_acc[2] = {};   // O^T[d = db*32 + (reg&3)+8*(reg>>2)+4h][q = l31]
    float l_part = 0.f;

    const f16* ktile = kb + (size_t)bh * 262144 + (size_t)sp * 131072;
    const f16* vtile = vtb + (size_t)bh * 262144 + (size_t)sp * 131072;

    const int sco = ((tid >> 2) * 4 + ((tid & 3) ^ ((tid >> 3) & 3))) * 8;
    const int ksw = (l31 >> 1) & 3;                // staging swizzle un-XOR
    const int wslot = w * 512;

    // tile 0 -> buf 0 via async glds (drained by first loop barrier)
    glds16(ktile + sco,        &K_lds[0][wslot]);
    glds16(ktile + 2048 + sco, &K_lds[0][2048 + wslot]);
    glds16(vtile + sco,        &V_lds[0][wslot]);
    glds16(vtile + 2048 + sco, &V_lds[0][2048 + wslot]);

    for (int kt = 0; kt < 32; ++kt) {
        const int cur = kt & 1;
        const f16* Kc = K_lds[cur];
        const f16* Vc = V_lds[cur];

        __syncthreads();   // glds(kt) drained; all waves done with buf cur^1

        // prefetch tile kt+1 into buf cur^1; overlaps compute of kt
        if (kt != 31) {
            ktile += 4096; vtile += 4096;
            glds16(ktile + sco,        &K_lds[cur ^ 1][wslot]);
            glds16(ktile + 2048 + sco, &K_lds[cur ^ 1][2048 + wslot]);
            glds16(vtile + sco,        &V_lds[cur ^ 1][wslot]);
            glds16(vtile + 2048 + sco, &V_lds[cur ^ 1][2048 + wslot]);
        }

#pragma unroll
        for (int mt = 0; mt < 2; ++mt) {
            // QK^T: A = K[tok = mt*32+l31][k], B = Q[q][k]
            f32x16 s = {};
            __builtin_amdgcn_s_setprio(1);
#pragma unroll
            for (int kc = 0; kc < 4; ++kc) {
                f16x8 ka = *(const f16x8*)&Kc[(kc >> 1) * 2048
                             + (mt * 32 + l31) * 32
                             + ((((kc & 1) * 2 + h) ^ ksw)) * 8];
                s = MFMA32_F16(ka, qa[kc], s);
            }
            __builtin_amdgcn_s_setprio(0);

            float pe[16];
#pragma unroll
            for (int i = 0; i < 16; ++i) pe[i] = __builtin_amdgcn_exp2f(s[i]);

            {   // l partial: rows with bit2 == h (partner half added in epilogue)
                float t0 = (pe[0] + pe[1]) + (pe[2] + pe[3]);
                float t1 = (pe[4] + pe[5]) + (pe[6] + pe[7]);
                float t2 = (pe[8] + pe[9]) + (pe[10] + pe[11]);
                float t3 = (pe[12] + pe[13]) + (pe[14] + pe[15]);
                l_part += (t0 + t1) + (t2 + t3);
            }

#pragma unroll
            for (int c = 0; c < 2; ++c) {
                // chunk c: regs cb..cb+7 hold in-chunk kk {4h..4h+3} u {8+4h..}
                const int cb = c * 8;
                unsigned X0 = pk16(pe[cb + 0], pe[cb + 1]);
                unsigned X1 = pk16(pe[cb + 2], pe[cb + 3]);
                unsigned Y0 = pk16(pe[cb + 4], pe[cb + 5]);
                unsigned Y1 = pk16(pe[cb + 6], pe[cb + 7]);
                // dst.hi <-> src.lo: r[0] = {X.lo, Y.lo}, r[1] = {X.hi, Y.hi}
                auto r0 = __builtin_amdgcn_permlane32_swap(X0, Y0, false, false);
                auto r1 = __builtin_amdgcn_permlane32_swap(X1, Y1, false, false);
                u32x4v pw;
                pw[0] = r0[0]; pw[1] = r1[0]; pw[2] = r0[1]; pw[3] = r1[1];
                f16x8 pfrag = __builtin_bit_cast(f16x8, pw);  // B[q][kk = 8h+j]

                const int kchunk = mt * 2 + c;
                __builtin_amdgcn_s_setprio(1);
#pragma unroll
                for (int db = 0; db < 2; ++db) {
                    f16x8 va = *(const f16x8*)&Vc[(kchunk >> 1) * 2048
                                 + (db * 32 + l31) * 32
                                 + (((((kchunk & 1) * 2 + h)) ^ ksw)) * 8];
                    o_acc[db] = MFMA32_F16(va, pfrag, o_acc[db]);
                }
                __builtin_amdgcn_s_setprio(0);
            }
        }
    }

    // epilogue: l = own half + partner half; write O^/l (f16) and l (f32).
    float lf = l_part + __shfl_xor(l_part, 32, 64);
    float inv = 1.0f / lf;
    const int row = w * 32 + l31;
    const size_t sb = (size_t)(sp * 32 + bh) * 2048 + qbase;
    if (h == 0) lsplit[sb + row] = lf;
    const size_t obase = (sb + row) * 64;
#pragma unroll
    for (int db = 0; db < 2; ++db) {
#pragma unroll
        for (int g = 0; g < 4; ++g) {
            f16x4v ov;
#pragma unroll
            for (int i = 0; i < 4; ++i)
                ov[i] = (f16)(o_acc[db][g * 4 + i] * inv);
            *(f16x4v*)&osplit[obase + db * 32 + g * 8 + h * 4] = ov;
        }
    }
}

// ---------------------------------------------------------------------------
// Output GEMM with FUSED combine (R11). 64x64 tiles, grid (64,16) = 1024
// blocks (4/CU). A-path reg-staged: per thread row r_ is FIXED; per iter
// load a1,a2 (osplit s0/s1) + l1,l2, merge (l1*a1+l2*a2)/(l1+l2),
// ds_write_b128 into As. B-path glds, 3-buf 2-deep. Iter end =
// lgkmcnt(0) + raw s_barrier (B stays in flight, T4). Ordering: compiler's
// wait for a(it+1) at the merge drains B(it+1) (issued before a(it+1)).
// LDS = 2*4 + 3*4 = 20 KB.
// ---------------------------------------------------------------------------
__global__ __launch_bounds__(256) void out_gemm(
    const f16* __restrict__ osplit, const float* __restrict__ lsplit,
    const f16* __restrict__ wt5, const float* __restrict__ bo,
    float* __restrict__ out)
{
    __shared__ alignas(16) f16 As[2][64 * 32];
    __shared__ alignas(16) f16 Bs[3][64 * 32];

    const int m0 = blockIdx.x * 64, n0 = blockIdx.y * 64;
    const int tid = threadIdx.x;
    const int w = tid >> 6, lane = tid & 63, quad = lane >> 4, l15 = lane & 15;
    const int wm = (w >> 1) * 32, wn = (w & 1) * 32;
    const int qsw = (quad ^ ((l15 >> 1) & 3)) * 8;
    const int r_ = (tid >> 2) & 63, c_ = (tid & 3) ^ ((tid >> 3) & 3);
    const int rowg = m0 + r_;
    const int b_ = rowg >> 11, tok = rowg & 2047;
    const int gB = (n0 + r_) * 1024 + c_ * 8;
    const int lslot = w * 512 + lane * 8;     // ds_write dest (f16 units)

    f32x4 acc[2][2] = {};

    // A fragment source for K-iter it: h = it>>1, d0 = (it&1)*32 + c_*8
#define OA(s, it) (&osplit[(((size_t)(s) * 32 + b_ * 16 + ((it) >> 1)) * 2048 \
                            + tok) * 64 + ((it) & 1) * 32 + c_ * 8])
#define OL(s, it) ((s) * 65536 + (b_ * 16 + ((it) >> 1)) * 2048 + tok)

    // merge a1,a2 with weights from l1,l2 and ds_write into As[buf]
#define MERGE_WRITE(buf, a1, a2, l1, l2)                                      \
    {                                                                         \
        float inv_ = 1.0f / ((l1) + (l2));                                    \
        float w1_ = (l1) * inv_, w2_ = (l2) * inv_;                           \
        f16x8 m_;                                                             \
        _Pragma("unroll")                                                     \
        for (int j_ = 0; j_ < 8; ++j_)                                        \
            m_[j_] = (f16)(w1_ * (float)(a1)[j_] + w2_ * (float)(a2)[j_]);    \
        *(f16x8*)&As[buf][lslot] = m_;                                        \
    }

    // prologue: B(0) first, then a(0) (so waiting a(0) drains B(0)), then B(1)
    glds16(&wt5[gB], &Bs[0][w * 512]);
    f16x8 a1 = *(const f16x8*)OA(0, 0);
    f16x8 a2 = *(const f16x8*)OA(1, 0);
    float l1 = lsplit[OL(0, 0)];
    float l2 = lsplit[OL(1, 0)];
    glds16(&wt5[gB + 32], &Bs[1][w * 512]);
    MERGE_WRITE(0, a1, a2, l1, l2)     // compiler waits a(0) -> B(0) drained
    asm volatile("s_waitcnt lgkmcnt(0)" ::: "memory");
    __builtin_amdgcn_s_barrier();
    // invariant entering iter it: outstanding vmem = B(it+1) only;
    // As[it&1] complete; Bs[it%3] drained.

    for (int it = 0; it < 32; ++it) {
        f16x8 na1, na2;
        float nl1, nl2;
        if (it < 31) {
            na1 = *(const f16x8*)OA(0, it + 1);
            na2 = *(const f16x8*)OA(1, it + 1);
            nl1 = lsplit[OL(0, it + 1)];
            nl2 = lsplit[OL(1, it + 1)];
            if (it + 2 < 32)
                glds16(&wt5[gB + (it + 2) * 32], &Bs[(it + 2) % 3][w * 512]);
        }

        const f16* Asc = As[it & 1];
        const f16* Bsc = Bs[it % 3];
        f16x8 a[2], b[2];
#pragma unroll
        for (int i = 0; i < 2; ++i)
            a[i] = *(const f16x8*)&Asc[(wm + i * 16 + l15) * 32 + qsw];
#pragma unroll
        for (int i = 0; i < 2; ++i)
            b[i] = *(const f16x8*)&Bsc[(wn + i * 16 + l15) * 32 + qsw];
#pragma unroll
        for (int mi = 0; mi < 2; ++mi)
#pragma unroll
            for (int ni = 0; ni < 2; ++ni)
                acc[mi][ni] = MFMA_F16(a[mi], b[ni], acc[mi][ni]);

        if (it < 31) {
            // compiler inserts vmcnt wait for na1/na2/nl here; B(it+1) was
            // issued BEFORE them so it drains too; B(it+2) stays in flight.
            MERGE_WRITE((it + 1) & 1, na1, na2, nl1, nl2)
        }
        asm volatile("s_waitcnt lgkmcnt(0)" ::: "memory");
        __builtin_amdgcn_s_barrier();
    }

#pragma unroll
    for (int mi = 0; mi < 2; ++mi) {
#pragma unroll
        for (int r = 0; r < 4; ++r) {
            int row = m0 + wm + mi * 16 + quad * 4 + r;
#pragma unroll
            for (int ni = 0; ni < 2; ++ni) {
                int col = n0 + wn + ni * 16 + l15;
                out[(size_t)row * 1024 + col] = acc[mi][ni][r] + bo[col];
            }
        }
    }
#undef OA
#undef OL
#undef MERGE_WRITE
}

// ---------------------------------------------------------------------------
// Host launcher
// ---------------------------------------------------------------------------
extern "C" void kernel_launch(void* const* d_in, const int* in_sizes, int n_in,
                              void* d_out, int out_size, void* d_ws, size_t ws_size,
                              hipStream_t stream)
{
    (void)in_sizes; (void)n_in; (void)out_size; (void)ws_size;

    const float* x    = (const float*)d_in[0];
    const float* ctx  = (const float*)d_in[1];
    const float* Wq   = (const float*)d_in[2];  const float* bq  = (const float*)d_in[3];
    const float* Wks  = (const float*)d_in[4];  const float* bks = (const float*)d_in[5];
    const float* Wvs  = (const float*)d_in[6];  const float* bvs = (const float*)d_in[7];
    const float* Wkc  = (const float*)d_in[8];  const float* bkc = (const float*)d_in[9];
    const float* Wvc  = (const float*)d_in[10]; const float* bvc = (const float*)d_in[11];
    const float* Wo   = (const float*)d_in[12]; const float* bo  = (const float*)d_in[13];

    char* ws = (char*)d_ws;
    f16*   xb     = (f16*)(ws + 0);          //  8 MB (dead after proj)
    f16*   cb     = (f16*)(ws + 8388608);    //  8 MB (dead after proj)
    f16*   vt     = (f16*)(ws + 0);          // 16 MB V^T tiles, reuses xb+cb
    f16*   wt     = (f16*)(ws + 16777216);   // 12 MB 6 x [1024][1024]
    float* lsplit = (float*)(ws + 16777216); // 512 KB, reuses dead Wq^T slice
    f16*   qbuf   = (f16*)(ws + 29360128);   //  8 MB [bh][2048][64]
    f16*   kbuf   = (f16*)(ws + 37748736);   // 16 MB K tiles
    f16*   vbuf   = (f16*)(ws + 54525952);   // 16 MB (dead after transpose_v)
    f16*   osplit = (f16*)(ws + 54525952);   // 16 MB, reuses vbuf

    prep<<<14336, 256, 0, stream>>>((const float4*)x, (const float4*)ctx,
                                    (f16x4v*)xb, (f16x4v*)cb,
                                    Wq, Wks, Wvs, Wkc, Wvc, Wo, wt);

    proj_gemm<<<dim3(32, 8, 5), 256, 0, stream>>>(
        xb, cb, wt, bq, bks, bkc, bvs, bvc, qbuf, kbuf, vbuf);

    transpose_v<<<dim3(16, 32), 256, 0, stream>>>(vbuf, vt);

    attn_kernel<<<dim3(32, 16, 2), 256, 0, stream>>>(qbuf, kbuf, vt, osplit, lsplit);

    out_gemm<<<dim3(64, 16), 256, 0, stream>>>(osplit, lsplit,
                                               wt + 5 * 1048576, bo, (float*)d_out);
}

// Round 12
// 306.966 us; speedup vs baseline: 1.0113x; 1.0014x over previous
//
#include <hip/hip_runtime.h>
#include <hip/hip_bf16.h>
#include <math.h>

// ---------------------------------------------------------------------------
// JointAttention fp16 MFMA pipeline, 5 dispatches:
//   prep (fp32->fp16 x/ctx + pack W^T) -> proj (fused 5-job QKV GEMM,
//   3-buf counted-vmcnt) -> transpose_v -> flash attn (S^T, TK=64, SPLIT-K2,
//   32x32 MFMA, in-register softmax, glds dbuf 1-barrier, 64 q-rows/wave) ->
//   out GEMM (64x64, combine FUSED into reg-staged A).
// R1: proj/out GEMM dbuf 1-barrier; setprio in attn.
// R3: attn on mfma_f32_32x32x16_f16: in-register P via permlane32_swap.
// R4/R5: split-K4 spill/NULL (register file caps waves/SIMD).
// R6/R7: no-LDS direct-global REFUTED (latency-bound).
// R8: attn K/V glds dbuf 1-barrier. R9: proj/out counted-vmcnt pipeline.
// R10: proj V^T-direct write REGRESSED (scatter) -- reverted.
// R11: combine fused into out_gemm (one dispatch fewer, ~neutral time).
// R12: attn 64 q-rows/WAVE (BQ=256, grid (32,8,2)=512): every wave was
//      reading the FULL 16KB K+V tile per iter (redundancy = waves/tile);
//      2 q-groups per wave reuse each ka/va fragment for 2x MFMAs ->
//      chip LDS read traffic halves (2.1GB->1.05GB). VGPR ~160 (o_acc 64
//      + qa 32 + ka/va 32), bounds(256,2) to forbid spill; 2 q-group
//      ILP chains compensate the occupancy drop.
// Swizzle: LDS chunk col c' = c ^ ((row>>1)&3) baked into staging global addr;
//   readers XOR with qsw/ksw.
// Layouts:
//   qbuf [bh][2048][64]              (Q pre-scaled by 0.125*log2e)
//   kbuf [bh][kt64][ks2][tok64][32]  (8KB contiguous staging tiles)
//   vbuf [bh][4096][64]  -> dead after transpose_v, reused as osplit
//   vt   [bh][kt64][kks2][d64][32]   (8KB contiguous V^T staging tiles)
//   osplit [s2][bh][2048][64] f16 (normalized partial O)   @ vbuf region
//   lsplit [s2][bh][2048] f32 (partial softmax denom)      @ dead Wq^T region
// ---------------------------------------------------------------------------

typedef _Float16 f16;
typedef _Float16 f16x8 __attribute__((ext_vector_type(8)));
typedef _Float16 f16x4v __attribute__((ext_vector_type(4)));
typedef _Float16 f16x2 __attribute__((ext_vector_type(2)));
typedef float    f32x4 __attribute__((ext_vector_type(4)));
typedef float    f32x16 __attribute__((ext_vector_type(16)));
typedef unsigned u32x4v __attribute__((ext_vector_type(4)));

#define MFMA_F16(a, b, c)  __builtin_amdgcn_mfma_f32_16x16x32_f16((a), (b), (c), 0, 0, 0)
#define MFMA32_F16(a, b, c) __builtin_amdgcn_mfma_f32_32x32x16_f16((a), (b), (c), 0, 0, 0)

#define QSCALE 0.18033688011112042f   // 0.125 * log2(e)

__device__ __forceinline__ void glds16(const f16* g, f16* l) {
    __builtin_amdgcn_global_load_lds(
        (const __attribute__((address_space(1))) void*)g,
        (__attribute__((address_space(3))) void*)l, 16, 0, 0);
}

// RNE f32x2 -> packed f16x2 (matches prior numerics; no RTZ risk)
__device__ __forceinline__ unsigned pk16(float a, float b) {
    f16x2 t = { (f16)a, (f16)b };
    return __builtin_bit_cast(unsigned, t);
}

// ---------------------------------------------------------------------------
// prep: blocks [0,8192) convert x/ctx fp32->fp16; [8192,14336) pack 6 W^T
// ---------------------------------------------------------------------------
__global__ __launch_bounds__(256) void prep(
    const float4* __restrict__ x, const float4* __restrict__ ctx,
    f16x4v* __restrict__ xb, f16x4v* __restrict__ cb,
    const float* __restrict__ W0, const float* __restrict__ W1,
    const float* __restrict__ W2, const float* __restrict__ W3,
    const float* __restrict__ W4, const float* __restrict__ W5,
    f16* __restrict__ wt)
{
    if (blockIdx.x < 8192) {
        const int n4 = (2 * 2048 * 1024) / 4;
        int i = blockIdx.x * 256 + threadIdx.x;
        float4 v;
        f16x4v* dst;
        if (i < n4) { v = x[i];        dst = xb + i; }
        else        { v = ctx[i - n4]; dst = cb + (i - n4); }
        f16x4v h = { (f16)v.x, (f16)v.y, (f16)v.z, (f16)v.w };
        *dst = h;
        return;
    }
    const int idx = blockIdx.x - 8192;
    const int z = idx >> 10, rem = idx & 1023;
    const float* Ws[6] = { W0, W1, W2, W3, W4, W5 };
    const float* W = Ws[z];
    f16* Wt = wt + (size_t)z * (1024 * 1024);

    __shared__ float tile[32][33];
    const int tx = threadIdx.x & 31, ty = threadIdx.x >> 5;
    const int n0 = (rem & 31) * 32, k0 = (rem >> 5) * 32;

#pragma unroll
    for (int i = 0; i < 4; ++i) {
        int r = i * 8 + ty;
        tile[r][tx] = W[(size_t)(k0 + r) * 1024 + n0 + tx];
    }
    __syncthreads();
#pragma unroll
    for (int i = 0; i < 4; ++i) {
        int r = i * 8 + ty;
        Wt[(size_t)(n0 + r) * 1024 + k0 + tx] = (f16)tile[tx][r];
    }
}

// Shared GEMM prologue (128-row A tile, BN-row B tile, BK=32, swizzled glds)
#define GEMM_PROLOGUE(BN)                                                     \
    const int m0 = blockIdx.x * 128, n0 = blockIdx.y * (BN);                  \
    const int tid = threadIdx.x;                                              \
    const int w = tid >> 6, lane = tid & 63, quad = lane >> 4, l15 = lane & 15;\
    const int wm = (w >> 1) * 64, wn = (w & 1) * ((BN) / 2);                  \
    const int qsw = (quad ^ ((l15 >> 1) & 3)) * 8;                            \
    int gA[2], gB[(BN) / 64];                                                 \
    _Pragma("unroll")                                                         \
    for (int p = 0; p < 2; ++p) {                                             \
        int s = tid + p * 256;                                                \
        int r = (s >> 2) & 127, c = (s & 3) ^ ((s >> 3) & 3);                 \
        gA[p] = (m0 + r) * 1024 + c * 8;                                      \
    }                                                                         \
    _Pragma("unroll")                                                         \
    for (int p = 0; p < (BN) / 64; ++p) {                                     \
        int s = tid + p * 256;                                                \
        int r = (s >> 2) & ((BN) - 1), c = (s & 3) ^ ((s >> 3) & 3);          \
        gB[p] = (n0 + r) * 1024 + c * 8;                                      \
    }

// Stage K-chunk koff into LDS buffer `buf` (no barriers; caller owns sync)
#define GEMM_STAGE_TO(BN, buf, koff)                                          \
    _Pragma("unroll")                                                         \
    for (int p = 0; p < 2; ++p)                                               \
        glds16(&A[gA[p] + (koff)], &As[buf][(p * 256 + w * 64) * 8]);         \
    _Pragma("unroll")                                                         \
    for (int p = 0; p < (BN) / 64; ++p)                                       \
        glds16(&Bt[gB[p] + (koff)], &Bs[buf][(p * 256 + w * 64) * 8]);

// ---------------------------------------------------------------------------
// Fused projection GEMM. z: 0=Q 1=K_self 2=K_ctx 3=V_self 4=V_ctx
// R9: 3-buffer 2-deep counted-vmcnt pipeline (T4). 4 glds/stage ->
// steady-state wait = vmcnt(4). LDS 48KB, 3 blocks/CU.
// ---------------------------------------------------------------------------
__global__ __launch_bounds__(256) void proj_gemm(
    const f16* __restrict__ xb, const f16* __restrict__ cb,
    const f16* __restrict__ wt,
    const float* __restrict__ bq, const float* __restrict__ bks,
    const float* __restrict__ bkc, const float* __restrict__ bvs,
    const float* __restrict__ bvc,
    f16* __restrict__ qbuf, f16* __restrict__ kbuf, f16* __restrict__ vbuf)
{
    __shared__ alignas(16) f16 As[3][128 * 32];
    __shared__ alignas(16) f16 Bs[3][128 * 32];

    const int z = blockIdx.z;
    const f16* A = (z == 0 || z == 1 || z == 3) ? xb : cb;
    const int wslot = (z == 0) ? 0 : (z == 1) ? 1 : (z == 2) ? 3 : (z == 3) ? 2 : 4;
    const f16* Bt = wt + (size_t)wslot * 1048576;
    const float* bias = (z == 0) ? bq : (z == 1) ? bks : (z == 2) ? bkc
                        : (z == 3) ? bvs : bvc;
    const int roff = (z == 2 || z == 4) ? 2048 : 0;

    GEMM_PROLOGUE(128)
    f32x4 acc[4][4] = {};

    GEMM_STAGE_TO(128, 0, 0)
    GEMM_STAGE_TO(128, 1, 32)

    for (int it = 0; it < 32; ++it) {
        // wait own glds(it) done (tile it+1's 4 loads may stay in flight)
        if (it < 31) { asm volatile("s_waitcnt vmcnt(4)" ::: "memory"); }
        else         { asm volatile("s_waitcnt vmcnt(0)" ::: "memory"); }
        __builtin_amdgcn_s_barrier();   // all waves' tile-it loads complete;
                                        // all waves done reading buf (it+2)%3
        if (it + 2 < 32) {
            GEMM_STAGE_TO(128, (it + 2) % 3, (it + 2) * 32)
        }
        const f16* Asc = As[it % 3];
        const f16* Bsc = Bs[it % 3];
        f16x8 a[4], b[4];
#pragma unroll
        for (int i = 0; i < 4; ++i)
            a[i] = *(const f16x8*)&Asc[(wm + i * 16 + l15) * 32 + qsw];
#pragma unroll
        for (int i = 0; i < 4; ++i)
            b[i] = *(const f16x8*)&Bsc[(wn + i * 16 + l15) * 32 + qsw];
#pragma unroll
        for (int mi = 0; mi < 4; ++mi)
#pragma unroll
            for (int ni = 0; ni < 4; ++ni)
                acc[mi][ni] = MFMA_F16(a[mi], b[ni], acc[mi][ni]);
    }

#pragma unroll
    for (int mi = 0; mi < 4; ++mi) {
#pragma unroll
        for (int r = 0; r < 4; ++r) {
            int row = m0 + wm + mi * 16 + quad * 4 + r;
            int b_ = row >> 11, tok = row & 2047;
#pragma unroll
            for (int ni = 0; ni < 4; ++ni) {
                int col = n0 + wn + ni * 16 + l15;
                float v = acc[mi][ni][r] + bias[col];
                int bh = b_ * 16 + (col >> 6);
                int tg = roff + tok;
                if (z == 0) {
                    qbuf[((size_t)bh * 2048 + tok) * 64 + (col & 63)] = (f16)(v * QSCALE);
                } else if (z <= 2) {
                    kbuf[(size_t)bh * 262144 + (size_t)(tg >> 6) * 4096
                         + (size_t)((col >> 5) & 1) * 2048 + (tg & 63) * 32 + (col & 31)] = (f16)v;
                } else {
                    vbuf[(size_t)bh * 262144 + (size_t)tg * 64 + (col & 63)] = (f16)v;
                }
            }
        }
    }
}

// ---------------------------------------------------------------------------
// V transpose: vbuf [bh][4096][64] -> vt tiles [bh][kt64][kks2][d64][32kk]
// ---------------------------------------------------------------------------
__global__ __launch_bounds__(256) void transpose_v(
    const f16* __restrict__ vbuf, f16* __restrict__ vt)
{
    const int t = threadIdx.x;
    const int mt = t >> 3, md = t & 7;
    const int tok0 = blockIdx.x * 256 + mt * 8;
    const int z = blockIdx.y;                   // bh
    f16x8 in[8];
#pragma unroll
    for (int i = 0; i < 8; ++i)
        in[i] = *(const f16x8*)&vbuf[((size_t)z * 4096 + tok0 + i) * 64 + md * 8];
    f16x8 ov[8];
#pragma unroll
    for (int j = 0; j < 8; ++j)
#pragma unroll
        for (int i = 0; i < 8; ++i) ov[j][i] = in[i][j];
    const int kt = tok0 >> 6, kks = (tok0 >> 5) & 1, kko = tok0 & 31;
#pragma unroll
    for (int j = 0; j < 8; ++j)
        *(f16x8*)&vt[(size_t)z * 262144 + (size_t)kt * 4096 + kks * 2048
                     + (md * 8 + j) * 32 + kko] = ov[j];
}

// ---------------------------------------------------------------------------
// Flash attention, S^T form, TK=64, SPLIT-K2 (each split: 32 key-tiles).
// R12: BQ=256/block, 64 q-rows per wave (2 q-groups). Grid (32,8,2)=512
// blocks (2/CU). Each wave reads ka[4]+va[4] ONCE per mt and feeds both
// q-groups -> LDS read traffic halved vs 32-q/wave. 2 independent q-group
// chains give intra-wave ILP at the lower occupancy. bounds(256,2): no
// spill possible (cap 256 regs).
// Per iter, per mt: ka[4],va[2][2] reads; per grp: S^T = 4 chained MFMA;
// pe=exp2; l_part[grp] += tree; pack+permlane32_swap -> pfrag;
// O^T[grp] += 4 MFMA.
// ---------------------------------------------------------------------------
__global__ __launch_bounds__(256, 2) void attn_kernel(
    const f16* __restrict__ q, const f16* __restrict__ kb,
    const f16* __restrict__ vtb, f16* __restrict__ osplit,
    float* __restrict__ lsplit)
{
    __shared__ alignas(16) f16 K_lds[2][4096];     // [buf][ks2][tok64][32]
    __shared__ alignas(16) f16 V_lds[2][4096];     // [buf][kks2][d64][32]

    const int tid = threadIdx.x;
    const int w = tid >> 6, lane = tid & 63;
    const int l31 = lane & 31, h = lane >> 5;
    const int bh = blockIdx.x, qt = blockIdx.y, sp = blockIdx.z;
    const int qbase = qt * 256;

    // Q fragments: B[q = l31][k = kc*16 + h*8 + j], 2 q-groups per wave
    f16x8 qa[2][4];
#pragma unroll
    for (int grp = 0; grp < 2; ++grp) {
        const size_t qrow =
            ((size_t)bh * 2048 + qbase + grp * 128 + w * 32 + l31) * 64;
#pragma unroll
        for (int kc = 0; kc < 4; ++kc)
            qa[grp][kc] = *(const f16x8*)&q[qrow + kc * 16 + h * 8];
    }

    f32x16 o_acc[2][2] = {};  // [grp][db]: O^T[d=db*32+(reg&3)+8*(reg>>2)+4h][q=l31]
    float l_part[2] = { 0.f, 0.f };

    const f16* ktile = kb + (size_t)bh * 262144 + (size_t)sp * 131072;
    const f16* vtile = vtb + (size_t)bh * 262144 + (size_t)sp * 131072;

    const int sco = ((tid >> 2) * 4 + ((tid & 3) ^ ((tid >> 3) & 3))) * 8;
    const int ksw = (l31 >> 1) & 3;                // staging swizzle un-XOR
    const int wslot = w * 512;

    // tile 0 -> buf 0 via async glds (drained by first loop barrier)
    glds16(ktile + sco,        &K_lds[0][wslot]);
    glds16(ktile + 2048 + sco, &K_lds[0][2048 + wslot]);
    glds16(vtile + sco,        &V_lds[0][wslot]);
    glds16(vtile + 2048 + sco, &V_lds[0][2048 + wslot]);

    for (int kt = 0; kt < 32; ++kt) {
        const int cur = kt & 1;
        const f16* Kc = K_lds[cur];
        const f16* Vc = V_lds[cur];

        __syncthreads();   // glds(kt) drained; all waves done with buf cur^1

        // prefetch tile kt+1 into buf cur^1; overlaps compute of kt
        if (kt != 31) {
            ktile += 4096; vtile += 4096;
            glds16(ktile + sco,        &K_lds[cur ^ 1][wslot]);
            glds16(ktile + 2048 + sco, &K_lds[cur ^ 1][2048 + wslot]);
            glds16(vtile + sco,        &V_lds[cur ^ 1][wslot]);
            glds16(vtile + 2048 + sco, &V_lds[cur ^ 1][2048 + wslot]);
        }

#pragma unroll
        for (int mt = 0; mt < 2; ++mt) {
            // shared fragment reads: once per mt, feed BOTH q-groups
            f16x8 ka[4];
#pragma unroll
            for (int kc = 0; kc < 4; ++kc)
                ka[kc] = *(const f16x8*)&Kc[(kc >> 1) * 2048
                             + (mt * 32 + l31) * 32
                             + ((((kc & 1) * 2 + h) ^ ksw)) * 8];
            f16x8 va[2][2];
#pragma unroll
            for (int c = 0; c < 2; ++c)
#pragma unroll
                for (int db = 0; db < 2; ++db) {
                    const int kchunk = mt * 2 + c;
                    va[c][db] = *(const f16x8*)&Vc[(kchunk >> 1) * 2048
                                 + (db * 32 + l31) * 32
                                 + ((((kchunk & 1) * 2 + h) ^ ksw)) * 8];
                }

#pragma unroll
            for (int grp = 0; grp < 2; ++grp) {
                // QK^T: A = K[tok = mt*32+l31][k], B = Q[q][k]
                f32x16 s = {};
                __builtin_amdgcn_s_setprio(1);
#pragma unroll
                for (int kc = 0; kc < 4; ++kc)
                    s = MFMA32_F16(ka[kc], qa[grp][kc], s);
                __builtin_amdgcn_s_setprio(0);

                float pe[16];
#pragma unroll
                for (int i = 0; i < 16; ++i) pe[i] = __builtin_amdgcn_exp2f(s[i]);

                {   // l partial: rows with bit2 == h (partner half in epilogue)
                    float t0 = (pe[0] + pe[1]) + (pe[2] + pe[3]);
                    float t1 = (pe[4] + pe[5]) + (pe[6] + pe[7]);
                    float t2 = (pe[8] + pe[9]) + (pe[10] + pe[11]);
                    float t3 = (pe[12] + pe[13]) + (pe[14] + pe[15]);
                    l_part[grp] += (t0 + t1) + (t2 + t3);
                }

#pragma unroll
                for (int c = 0; c < 2; ++c) {
                    // chunk c: regs cb..cb+7 = in-chunk kk {4h..} u {8+4h..}
                    const int cb = c * 8;
                    unsigned X0 = pk16(pe[cb + 0], pe[cb + 1]);
                    unsigned X1 = pk16(pe[cb + 2], pe[cb + 3]);
                    unsigned Y0 = pk16(pe[cb + 4], pe[cb + 5]);
                    unsigned Y1 = pk16(pe[cb + 6], pe[cb + 7]);
                    // dst.hi<->src.lo: r[0]={X.lo,Y.lo}, r[1]={X.hi,Y.hi}
                    auto r0 = __builtin_amdgcn_permlane32_swap(X0, Y0, false, false);
                    auto r1 = __builtin_amdgcn_permlane32_swap(X1, Y1, false, false);
                    u32x4v pw;
                    pw[0] = r0[0]; pw[1] = r1[0]; pw[2] = r0[1]; pw[3] = r1[1];
                    f16x8 pfrag = __builtin_bit_cast(f16x8, pw); // B[q][kk=8h+j]

                    __builtin_amdgcn_s_setprio(1);
#pragma unroll
                    for (int db = 0; db < 2; ++db)
                        o_acc[grp][db] = MFMA32_F16(va[c][db], pfrag, o_acc[grp][db]);
                    __builtin_amdgcn_s_setprio(0);
                }
            }
        }
    }

    // epilogue: l = own half + partner half; write O^/l (f16) and l (f32).
    const size_t sb = (size_t)(sp * 32 + bh) * 2048 + qbase;
#pragma unroll
    for (int grp = 0; grp < 2; ++grp) {
        float lf = l_part[grp] + __shfl_xor(l_part[grp], 32, 64);
        float inv = 1.0f / lf;
        const int rowl = grp * 128 + w * 32 + l31;
        if (h == 0) lsplit[sb + rowl] = lf;
        const size_t obase = (sb + rowl) * 64;
#pragma unroll
        for (int db = 0; db < 2; ++db) {
#pragma unroll
            for (int g = 0; g < 4; ++g) {
                f16x4v ov;
#pragma unroll
                for (int i = 0; i < 4; ++i)
                    ov[i] = (f16)(o_acc[grp][db][g * 4 + i] * inv);
                *(f16x4v*)&osplit[obase + db * 32 + g * 8 + h * 4] = ov;
            }
        }
    }
}

// ---------------------------------------------------------------------------
// Output GEMM with FUSED combine (R11). 64x64 tiles, grid (64,16) = 1024
// blocks (4/CU). A-path reg-staged: per thread row r_ is FIXED; per iter
// load a1,a2 (osplit s0/s1) + l1,l2, merge (l1*a1+l2*a2)/(l1+l2),
// ds_write_b128 into As. B-path glds, 3-buf 2-deep. Iter end =
// lgkmcnt(0) + raw s_barrier (B stays in flight, T4).
// ---------------------------------------------------------------------------
__global__ __launch_bounds__(256) void out_gemm(
    const f16* __restrict__ osplit, const float* __restrict__ lsplit,
    const f16* __restrict__ wt5, const float* __restrict__ bo,
    float* __restrict__ out)
{
    __shared__ alignas(16) f16 As[2][64 * 32];
    __shared__ alignas(16) f16 Bs[3][64 * 32];

    const int m0 = blockIdx.x * 64, n0 = blockIdx.y * 64;
    const int tid = threadIdx.x;
    const int w = tid >> 6, lane = tid & 63, quad = lane >> 4, l15 = lane & 15;
    const int wm = (w >> 1) * 32, wn = (w & 1) * 32;
    const int qsw = (quad ^ ((l15 >> 1) & 3)) * 8;
    const int r_ = (tid >> 2) & 63, c_ = (tid & 3) ^ ((tid >> 3) & 3);
    const int rowg = m0 + r_;
    const int b_ = rowg >> 11, tok = rowg & 2047;
    const int gB = (n0 + r_) * 1024 + c_ * 8;
    const int lslot = w * 512 + lane * 8;     // ds_write dest (f16 units)

    f32x4 acc[2][2] = {};

    // A fragment source for K-iter it: h = it>>1, d0 = (it&1)*32 + c_*8
#define OA(s, it) (&osplit[(((size_t)(s) * 32 + b_ * 16 + ((it) >> 1)) * 2048 \
                            + tok) * 64 + ((it) & 1) * 32 + c_ * 8])
#define OL(s, it) ((s) * 65536 + (b_ * 16 + ((it) >> 1)) * 2048 + tok)

    // merge a1,a2 with weights from l1,l2 and ds_write into As[buf]
#define MERGE_WRITE(buf, a1, a2, l1, l2)                                      \
    {                                                                         \
        float inv_ = 1.0f / ((l1) + (l2));                                    \
        float w1_ = (l1) * inv_, w2_ = (l2) * inv_;                           \
        f16x8 m_;                                                             \
        _Pragma("unroll")                                                     \
        for (int j_ = 0; j_ < 8; ++j_)                                        \
            m_[j_] = (f16)(w1_ * (float)(a1)[j_] + w2_ * (float)(a2)[j_]);    \
        *(f16x8*)&As[buf][lslot] = m_;                                        \
    }

    // prologue: B(0) first, then a(0) (so waiting a(0) drains B(0)), then B(1)
    glds16(&wt5[gB], &Bs[0][w * 512]);
    f16x8 a1 = *(const f16x8*)OA(0, 0);
    f16x8 a2 = *(const f16x8*)OA(1, 0);
    float l1 = lsplit[OL(0, 0)];
    float l2 = lsplit[OL(1, 0)];
    glds16(&wt5[gB + 32], &Bs[1][w * 512]);
    MERGE_WRITE(0, a1, a2, l1, l2)     // compiler waits a(0) -> B(0) drained
    asm volatile("s_waitcnt lgkmcnt(0)" ::: "memory");
    __builtin_amdgcn_s_barrier();
    // invariant entering iter it: outstanding vmem = B(it+1) only;
    // As[it&1] complete; Bs[it%3] drained.

    for (int it = 0; it < 32; ++it) {
        f16x8 na1, na2;
        float nl1, nl2;
        if (it < 31) {
            na1 = *(const f16x8*)OA(0, it + 1);
            na2 = *(const f16x8*)OA(1, it + 1);
            nl1 = lsplit[OL(0, it + 1)];
            nl2 = lsplit[OL(1, it + 1)];
            if (it + 2 < 32)
                glds16(&wt5[gB + (it + 2) * 32], &Bs[(it + 2) % 3][w * 512]);
        }

        const f16* Asc = As[it & 1];
        const f16* Bsc = Bs[it % 3];
        f16x8 a[2], b[2];
#pragma unroll
        for (int i = 0; i < 2; ++i)
            a[i] = *(const f16x8*)&Asc[(wm + i * 16 + l15) * 32 + qsw];
#pragma unroll
        for (int i = 0; i < 2; ++i)
            b[i] = *(const f16x8*)&Bsc[(wn + i * 16 + l15) * 32 + qsw];
#pragma unroll
        for (int mi = 0; mi < 2; ++mi)
#pragma unroll
            for (int ni = 0; ni < 2; ++ni)
                acc[mi][ni] = MFMA_F16(a[mi], b[ni], acc[mi][ni]);

        if (it < 31) {
            // compiler inserts vmcnt wait for na1/na2/nl here; B(it+1) was
            // issued BEFORE them so it drains too; B(it+2) stays in flight.
            MERGE_WRITE((it + 1) & 1, na1, na2, nl1, nl2)
        }
        asm volatile("s_waitcnt lgkmcnt(0)" ::: "memory");
        __builtin_amdgcn_s_barrier();
    }

#pragma unroll
    for (int mi = 0; mi < 2; ++mi) {
#pragma unroll
        for (int r = 0; r < 4; ++r) {
            int row = m0 + wm + mi * 16 + quad * 4 + r;
#pragma unroll
            for (int ni = 0; ni < 2; ++ni) {
                int col = n0 + wn + ni * 16 + l15;
                out[(size_t)row * 1024 + col] = acc[mi][ni][r] + bo[col];
            }
        }
    }
#undef OA
#undef OL
#undef MERGE_WRITE
}

// ---------------------------------------------------------------------------
// Host launcher
// ---------------------------------------------------------------------------
extern "C" void kernel_launch(void* const* d_in, const int* in_sizes, int n_in,
                              void* d_out, int out_size, void* d_ws, size_t ws_size,
                              hipStream_t stream)
{
    (void)in_sizes; (void)n_in; (void)out_size; (void)ws_size;

    const float* x    = (const float*)d_in[0];
    const float* ctx  = (const float*)d_in[1];
    const float* Wq   = (const float*)d_in[2];  const float* bq  = (const float*)d_in[3];
    const float* Wks  = (const float*)d_in[4];  const float* bks = (const float*)d_in[5];
    const float* Wvs  = (const float*)d_in[6];  const float* bvs = (const float*)d_in[7];
    const float* Wkc  = (const float*)d_in[8];  const float* bkc = (const float*)d_in[9];
    const float* Wvc  = (const float*)d_in[10]; const float* bvc = (const float*)d_in[11];
    const float* Wo   = (const float*)d_in[12]; const float* bo  = (const float*)d_in[13];

    char* ws = (char*)d_ws;
    f16*   xb     = (f16*)(ws + 0);          //  8 MB (dead after proj)
    f16*   cb     = (f16*)(ws + 8388608);    //  8 MB (dead after proj)
    f16*   vt     = (f16*)(ws + 0);          // 16 MB V^T tiles, reuses xb+cb
    f16*   wt     = (f16*)(ws + 16777216);   // 12 MB 6 x [1024][1024]
    float* lsplit = (float*)(ws + 16777216); // 512 KB, reuses dead Wq^T slice
    f16*   qbuf   = (f16*)(ws + 29360128);   //  8 MB [bh][2048][64]
    f16*   kbuf   = (f16*)(ws + 37748736);   // 16 MB K tiles
    f16*   vbuf   = (f16*)(ws + 54525952);   // 16 MB (dead after transpose_v)
    f16*   osplit = (f16*)(ws + 54525952);   // 16 MB, reuses vbuf

    prep<<<14336, 256, 0, stream>>>((const float4*)x, (const float4*)ctx,
                                    (f16x4v*)xb, (f16x4v*)cb,
                                    Wq, Wks, Wvs, Wkc, Wvc, Wo, wt);

    proj_gemm<<<dim3(32, 8, 5), 256, 0, stream>>>(
        xb, cb, wt, bq, bks, bkc, bvs, bvc, qbuf, kbuf, vbuf);

    transpose_v<<<dim3(16, 32), 256, 0, stream>>>(vbuf, vt);

    attn_kernel<<<dim3(32, 8, 2), 256, 0, stream>>>(qbuf, kbuf, vt, osplit, lsplit);

    out_gemm<<<dim3(64, 16), 256, 0, stream>>>(osplit, lsplit,
                                               wt + 5 * 1048576, bo, (float*)d_out);
}